// Round 9
// baseline (852.695 us; speedup 1.0000x reference)
//
#include <hip/hip_runtime.h>

// MoE Transformer block, MI355X/gfx950. B=2,S=4096,D=1024,H=16,BS=64,E=8,HD=64.
//
// ALL INPUTS/OUTPUT ARE FP32. Gating argmax needs ~1e-6 logit fidelity, so
// QKV and Wo GEMMs use EXACT 3-way bf16 splits with 6 MFMA passes. Attention
// is pure fp32 VALU. MoE GEMM is 1-pass bf16.
//
// R16 (attn LDS-read reduction + moe XCD clustering; both bit-identical):
//  - attn QK^T loop-swap: d outer, j inner -> Qs row read 16x instead of
//    256x per thread (512 -> 272 b128 reads). Identical accumulation order
//    per (qi,kj) -> bitwise identical output.
//  - moe: block-index remap d = y + 8m + 160z so all 20 m-blocks of a
//    B-panel (n0,e) share disp%8 -> one XCD's L2 holds each panel (2 MB).
//  - everything else identical to R15 (SLAB=2560 serial qkv->attn,
//    peak ws = 40,239,104 B exactly).

typedef unsigned short u16;
typedef __attribute__((ext_vector_type(8))) short short8;
typedef __attribute__((ext_vector_type(4))) short short4v;
typedef __attribute__((ext_vector_type(4))) float f32x4;

static constexpr int KD = 1024;
static constexpr int NTOK = 8192;
static constexpr int SLAB = 2560;   // 20 x 128; slabs 2560,2560,2560,512

__device__ inline u16 f2bf(float x) {
  union { float f; unsigned u; } c; c.f = x;
  unsigned r = c.u + 0x7fffu + ((c.u >> 16) & 1u);
  return (u16)(r >> 16);
}
__device__ inline float bf2f(u16 b) {
  union { unsigned u; float f; } c; c.u = ((unsigned)b) << 16; return c.f;
}
__device__ inline float scrub(float x) {   // finite -> x, else 0
  return (x == x && fabsf(x) < 1e30f) ? x : 0.0f;
}
struct Split3 { short h, m, l; };
__device__ inline Split3 split3(float a) {
  Split3 s;
  u16 hb = f2bf(a); float r1 = a - bf2f(hb);   // exact
  u16 mb = f2bf(r1); float r2 = r1 - bf2f(mb); // exact
  s.h = (short)hb; s.m = (short)mb; s.l = (short)f2bf(r2);
  return s;
}

// ---------------- one-time: W[k][n] fp32 -> planes [n][k] bf16 (split3)
// z = blockIdx.z + z_base: 0..2 -> wqkv plane sets, 3 -> wo plane set.
__global__ __launch_bounds__(256) void prep_w(
    const float* __restrict__ Wq, const float* __restrict__ Wk,
    const float* __restrict__ Wv, const float* __restrict__ Wo,
    u16* __restrict__ wqkv, u16* __restrict__ wop, int z_base) {
  const int z = blockIdx.z + z_base;
  const float* W = z == 0 ? Wq : z == 1 ? Wk : z == 2 ? Wv : Wo;
  u16* ph_ = (z < 3) ? (wqkv + (size_t)z * 3145728) : wop;
  u16* pm_ = ph_ + 1048576;
  u16* pl_ = pm_ + 1048576;
  const int k0 = blockIdx.x * 64, n0 = blockIdx.y * 64;
  __shared__ u16 Th[64][80], Tm[64][80], Tl[64][80];
  const int tid = threadIdx.x;
  {
    const int r = tid >> 2, c0 = (tid & 3) * 16;
    const float* wp = &W[(size_t)(k0 + r) * KD + n0 + c0];
    for (int u = 0; u < 16; u++) {
      Split3 s = split3(wp[u]);
      Th[c0 + u][r] = (u16)s.h; Tm[c0 + u][r] = (u16)s.m; Tl[c0 + u][r] = (u16)s.l;
    }
  }
  __syncthreads();
  {
    const int n = tid >> 2, kc = (tid & 3) * 16;
    size_t off = (size_t)(n0 + n) * KD + k0 + kc;
    *(short8*)&ph_[off]     = *(const short8*)&Th[n][kc];
    *(short8*)&ph_[off + 8] = *(const short8*)&Th[n][kc + 8];
    *(short8*)&pm_[off]     = *(const short8*)&Tm[n][kc];
    *(short8*)&pm_[off + 8] = *(const short8*)&Tm[n][kc + 8];
    *(short8*)&pl_[off]     = *(const short8*)&Tl[n][kc];
    *(short8*)&pl_[off + 8] = *(const short8*)&Tl[n][kc + 8];
  }
}

// ---------------- one-time: We[e][k][n] fp32 -> bf16 [e*1024+n] rows, stored
// in the SECOND half (u16 offset row*2048+1024) of each t row (after ln_gate).
__global__ __launch_bounds__(256) void prep_we(
    const float* __restrict__ We, u16* __restrict__ t16) {
  const int e = blockIdx.z;
  const int k0 = blockIdx.x * 64, n0 = blockIdx.y * 64;
  __shared__ u16 T[64][80];
  const int tid = threadIdx.x;
  {
    const int r = tid >> 2, c0 = (tid & 3) * 16;
    const float* wp = &We[((size_t)e * KD + k0 + r) * KD + n0 + c0];
    for (int u = 0; u < 16; u++) T[c0 + u][r] = f2bf(wp[u]);
  }
  __syncthreads();
  {
    const int n = tid >> 2, kc = (tid & 3) * 16;
    size_t off = ((size_t)(e * 1024 + n0 + n)) * 2048 + 1024 + k0 + kc;
    *(short8*)&t16[off]     = *(const short8*)&T[n][kc];
    *(short8*)&t16[off + 8] = *(const short8*)&T[n][kc + 8];
  }
}

// ---------------- shared pieces for the 128x128 6-pass split GEMMs ----------
__device__ inline void qload(const float* aB, const u16* bBh, const u16* bBm,
                             const u16* bBl, int kk, f32x4* A, short8* B) {
#pragma unroll
  for (int u = 0; u < 4; u++) A[u] = *(const f32x4*)(aB + kk + 4 * u);
  B[0] = *(const short8*)(bBh + kk); B[1] = *(const short8*)(bBh + kk + 8);
  B[2] = *(const short8*)(bBm + kk); B[3] = *(const short8*)(bBm + kk + 8);
  B[4] = *(const short8*)(bBl + kk); B[5] = *(const short8*)(bBl + kk + 8);
}

__device__ inline void qstage(const f32x4* A, const short8* B,
    u16 (*Ah)[40], u16 (*Am)[40], u16 (*Al)[40],
    u16 (*Bh)[40], u16 (*Bm)[40], u16 (*Bl)[40], int sr, int sc) {
  short8 h0, h1, mm0, mm1, l0, l1;
#pragma unroll
  for (int u = 0; u < 8; u++) {
    Split3 s = split3(A[u >> 2][u & 3]);
    h0[u] = s.h; mm0[u] = s.m; l0[u] = s.l;
  }
#pragma unroll
  for (int u = 0; u < 8; u++) {
    Split3 s = split3(A[2 + (u >> 2)][u & 3]);
    h1[u] = s.h; mm1[u] = s.m; l1[u] = s.l;
  }
  *(short8*)&Ah[sr][sc] = h0;  *(short8*)&Ah[sr][sc + 8] = h1;
  *(short8*)&Am[sr][sc] = mm0; *(short8*)&Am[sr][sc + 8] = mm1;
  *(short8*)&Al[sr][sc] = l0;  *(short8*)&Al[sr][sc + 8] = l1;
  *(short8*)&Bh[sr][sc] = B[0]; *(short8*)&Bh[sr][sc + 8] = B[1];
  *(short8*)&Bm[sr][sc] = B[2]; *(short8*)&Bm[sr][sc + 8] = B[3];
  *(short8*)&Bl[sr][sc] = B[4]; *(short8*)&Bl[sr][sc + 8] = B[5];
}

__device__ inline void qcompute(
    const u16 (*Ah)[40], const u16 (*Am)[40], const u16 (*Al)[40],
    const u16 (*Bh)[40], const u16 (*Bm)[40], const u16 (*Bl)[40],
    int wm, int wn, int quad, int l15, f32x4 (*acc)[4]) {
  short8 ah[4], am[4], al[4];
#pragma unroll
  for (int i = 0; i < 4; i++) {
    ah[i] = *(const short8*)&Ah[wm + 16 * i + l15][quad * 8];
    am[i] = *(const short8*)&Am[wm + 16 * i + l15][quad * 8];
    al[i] = *(const short8*)&Al[wm + 16 * i + l15][quad * 8];
  }
#pragma unroll
  for (int j = 0; j < 4; j++) {
    short8 bh = *(const short8*)&Bh[wn + 16 * j + l15][quad * 8];
    short8 bm = *(const short8*)&Bm[wn + 16 * j + l15][quad * 8];
    short8 bl = *(const short8*)&Bl[wn + 16 * j + l15][quad * 8];
#pragma unroll
    for (int i = 0; i < 4; i++) {
      f32x4 a = acc[i][j];
      a = __builtin_amdgcn_mfma_f32_16x16x32_bf16(al[i], bh, a, 0, 0, 0);
      a = __builtin_amdgcn_mfma_f32_16x16x32_bf16(am[i], bm, a, 0, 0, 0);
      a = __builtin_amdgcn_mfma_f32_16x16x32_bf16(ah[i], bl, a, 0, 0, 0);
      a = __builtin_amdgcn_mfma_f32_16x16x32_bf16(am[i], bh, a, 0, 0, 0);
      a = __builtin_amdgcn_mfma_f32_16x16x32_bf16(ah[i], bm, a, 0, 0, 0);
      a = __builtin_amdgcn_mfma_f32_16x16x32_bf16(ah[i], bh, a, 0, 0, 0);
      acc[i][j] = a;
    }
  }
}

// ---------------- fused QKV GEMM (slab), 128x128 tile, 6-pass, prefetched.
// q -> d_out rows of this slab; k,v -> workspace slab buffers.
__global__ __launch_bounds__(256, 2) void qkv_gemm(
    const float* __restrict__ x, const u16* __restrict__ wt,
    const float* __restrict__ bq, const float* __restrict__ bk,
    const float* __restrict__ bv,
    float* __restrict__ qo, float* __restrict__ ko, float* __restrict__ vo,
    int tok0) {
  const int m0 = blockIdx.x * 128, n0 = blockIdx.y * 128, z = blockIdx.z;
  const u16* Wh = wt + (size_t)z * 3145728;
  const u16* Wm = Wh + 1048576;
  const u16* Wl = Wm + 1048576;
  const float* bias = z == 0 ? bq : z == 1 ? bk : bv;
  float* outp = z == 0 ? qo : z == 1 ? ko : vo;
  __shared__ u16 Ah[128][40], Am[128][40], Al[128][40];
  __shared__ u16 Bh[128][40], Bm[128][40], Bl[128][40];
  const int tid = threadIdx.x, lane = tid & 63, wv = tid >> 6;
  const int wm = (wv >> 1) * 64, wn = (wv & 1) * 64;
  const int quad = lane >> 4, l15 = lane & 15;
  const int sr = tid >> 1, sc = (tid & 1) * 16;
  const float* aB = &x[(size_t)(tok0 + m0 + sr) * KD + sc];
  const u16* bBh = &Wh[(size_t)(n0 + sr) * KD + sc];
  const u16* bBm = &Wm[(size_t)(n0 + sr) * KD + sc];
  const u16* bBl = &Wl[(size_t)(n0 + sr) * KD + sc];
  f32x4 acc[4][4] = {};
  f32x4 A0[4], A1[4]; short8 B0[6], B1[6];
  qload(aB, bBh, bBm, bBl, 0, A0, B0);
  for (int k0 = 0; k0 < KD; k0 += 64) {
    qstage(A0, B0, Ah, Am, Al, Bh, Bm, Bl, sr, sc);
    qload(aB, bBh, bBm, bBl, k0 + 32, A1, B1);
    __syncthreads();
    qcompute(Ah, Am, Al, Bh, Bm, Bl, wm, wn, quad, l15, acc);
    __syncthreads();
    qstage(A1, B1, Ah, Am, Al, Bh, Bm, Bl, sr, sc);
    if (k0 + 64 < KD) qload(aB, bBh, bBm, bBl, k0 + 64, A0, B0);
    __syncthreads();
    qcompute(Ah, Am, Al, Bh, Bm, Bl, wm, wn, quad, l15, acc);
    __syncthreads();
  }
  for (int j = 0; j < 4; j++) {
    int n = n0 + wn + 16 * j + l15;
    float bb = bias[n];
    for (int i = 0; i < 4; i++) {
      int mb = m0 + wm + 16 * i + quad * 4;
      for (int r = 0; r < 4; r++)
        outp[(size_t)(mb + r) * KD + n] = scrub(acc[i][j][r] + bb);
    }
  }
}

// ---------------- block-local attention, fp32 VALU; o in-place over q rows.
// kj = part + 4*j (conflict-free, R15). QK^T loop-swapped: d outer, j inner
// -> Q row read once per d-group (16 b128) instead of once per (j,d) (256).
// Accumulation order per (qi,kj) unchanged -> bitwise identical.
__global__ __launch_bounds__(256) void attn_fp32(
    float* __restrict__ q, const float* __restrict__ k,
    const float* __restrict__ v) {
  const int nb = blockIdx.x >> 4, h = blockIdx.x & 15;
  const size_t base = (size_t)(nb * 64) * KD + h * 64;
  __shared__ float Qs[64][68], Ks[64][68], Vs[64][68];
  const int tid = threadIdx.x;
  {
    const int r = tid >> 2, c0 = (tid & 3) * 16;
    const float* qp = &q[base + (size_t)r * KD + c0];
    const float* kp = &k[base + (size_t)r * KD + c0];
    const float* vp = &v[base + (size_t)r * KD + c0];
    for (int u = 0; u < 16; u += 4) {
      *(float4*)&Qs[r][c0 + u] = *(const float4*)(qp + u);
      *(float4*)&Ks[r][c0 + u] = *(const float4*)(kp + u);
      *(float4*)&Vs[r][c0 + u] = *(const float4*)(vp + u);
    }
  }
  __syncthreads();
  const int qi = tid >> 2, part = tid & 3;
  float sc[16];
#pragma unroll
  for (int j = 0; j < 16; j++) sc[j] = 0.f;
  for (int d = 0; d < 64; d += 4) {
    float4 qv = *(const float4*)&Qs[qi][d];
#pragma unroll
    for (int j = 0; j < 16; j++) {
      const int kj = part + 4 * j;
      float4 kv = *(const float4*)&Ks[kj][d];
      sc[j] += qv.x * kv.x + qv.y * kv.y + qv.z * kv.z + qv.w * kv.w;
    }
  }
#pragma unroll
  for (int j = 0; j < 16; j++) sc[j] *= 0.125f;
  float mx = sc[0];
  for (int j = 1; j < 16; j++) mx = fmaxf(mx, sc[j]);
  mx = fmaxf(mx, __shfl_xor(mx, 1, 64));
  mx = fmaxf(mx, __shfl_xor(mx, 2, 64));
  float sum = 0.f;
  for (int j = 0; j < 16; j++) { sc[j] = expf(sc[j] - mx); sum += sc[j]; }
  sum += __shfl_xor(sum, 1, 64);
  sum += __shfl_xor(sum, 2, 64);
  const float inv = 1.0f / sum;
  float po[64];
  for (int d = 0; d < 64; d++) po[d] = 0.f;
  for (int j = 0; j < 16; j++) {
    const float pv = sc[j] * inv;
    const int kj = part + 4 * j;
    for (int d = 0; d < 64; d += 4) {
      float4 vv = *(const float4*)&Vs[kj][d];
      po[d]     += pv * vv.x; po[d + 1] += pv * vv.y;
      po[d + 2] += pv * vv.z; po[d + 3] += pv * vv.w;
    }
  }
  for (int d = 0; d < 64; d++) {
    po[d] += __shfl_xor(po[d], 1, 64);
    po[d] += __shfl_xor(po[d], 2, 64);
  }
#pragma unroll
  for (int d0 = 0; d0 < 64; d0 += 16)
    if ((d0 >> 4) == part) {
#pragma unroll
      for (int u = 0; u < 16; u += 4) {
        float4 st; st.x = scrub(po[d0 + u]);     st.y = scrub(po[d0 + u + 1]);
                   st.z = scrub(po[d0 + u + 2]); st.w = scrub(po[d0 + u + 3]);
        *(float4*)&q[base + (size_t)qi * KD + d0 + u] = st;
      }
    }
}

// ---------------- Wo GEMM (full-token), 6-pass split-bf16: t = o @ Wo + bo + x
__global__ __launch_bounds__(256, 2) void wo_gemm(
    const float* __restrict__ o, const u16* __restrict__ wto,
    const float* __restrict__ bo, const float* __restrict__ xin,
    float* __restrict__ t) {
  const int m0 = blockIdx.x * 128, n0 = blockIdx.y * 128;
  const u16* Wh = wto;
  const u16* Wm = Wh + 1048576;
  const u16* Wl = Wm + 1048576;
  __shared__ u16 Ah[128][40], Am[128][40], Al[128][40];
  __shared__ u16 Bh[128][40], Bm[128][40], Bl[128][40];
  const int tid = threadIdx.x, lane = tid & 63, wv = tid >> 6;
  const int wm = (wv >> 1) * 64, wn = (wv & 1) * 64;
  const int quad = lane >> 4, l15 = lane & 15;
  const int sr = tid >> 1, sc = (tid & 1) * 16;
  const float* aB = &o[(size_t)(m0 + sr) * KD + sc];
  const u16* bBh = &Wh[(size_t)(n0 + sr) * KD + sc];
  const u16* bBm = &Wm[(size_t)(n0 + sr) * KD + sc];
  const u16* bBl = &Wl[(size_t)(n0 + sr) * KD + sc];
  f32x4 acc[4][4] = {};
  f32x4 A0[4], A1[4]; short8 B0[6], B1[6];
  qload(aB, bBh, bBm, bBl, 0, A0, B0);
  for (int k0 = 0; k0 < KD; k0 += 64) {
    qstage(A0, B0, Ah, Am, Al, Bh, Bm, Bl, sr, sc);
    qload(aB, bBh, bBm, bBl, k0 + 32, A1, B1);
    __syncthreads();
    qcompute(Ah, Am, Al, Bh, Bm, Bl, wm, wn, quad, l15, acc);
    __syncthreads();
    qstage(A1, B1, Ah, Am, Al, Bh, Bm, Bl, sr, sc);
    if (k0 + 64 < KD) qload(aB, bBh, bBm, bBl, k0 + 64, A0, B0);
    __syncthreads();
    qcompute(Ah, Am, Al, Bh, Bm, Bl, wm, wn, quad, l15, acc);
    __syncthreads();
  }
  for (int j = 0; j < 4; j++) {
    int n = n0 + wn + 16 * j + l15;
    float bb = bo[n];
    for (int i = 0; i < 4; i++) {
      int mb = m0 + wm + 16 * i + quad * 4;
      for (int r = 0; r < 4; r++) {
        size_t off = (size_t)(mb + r) * KD + n;
        t[off] = scrub(acc[i][j][r] + bb + xin[off]);
      }
    }
  }
}

// ---------------- LayerNorm + gating + bucketing; h16 in-place over t rows
__global__ __launch_bounds__(256) void ln_gate(
    const float* __restrict__ t, const float* __restrict__ gamma,
    const float* __restrict__ beta, const float* __restrict__ Wg,
    float* __restrict__ gate, int* __restrict__ idx, int* __restrict__ cnt,
    u16* __restrict__ t16) {
  const int tok = blockIdx.x;
  const int tid = threadIdx.x, lane = tid & 63, wv = tid >> 6;
  const float* row = t + (size_t)tok * KD;
  float4 xv = *(const float4*)&row[tid * 4];
  __shared__ float red[4];
  __shared__ float rg[4][8];
  float s = xv.x + xv.y + xv.z + xv.w;
  for (int off = 32; off; off >>= 1) s += __shfl_down(s, off, 64);
  if (lane == 0) red[wv] = s;
  __syncthreads();
  float mu = (red[0] + red[1] + red[2] + red[3]) * (1.0f / 1024.0f);
  __syncthreads();
  float d0 = xv.x - mu, d1 = xv.y - mu, d2 = xv.z - mu, d3 = xv.w - mu;
  float ss = d0 * d0 + d1 * d1 + d2 * d2 + d3 * d3;
  for (int off = 32; off; off >>= 1) ss += __shfl_down(ss, off, 64);
  if (lane == 0) red[wv] = ss;
  __syncthreads();
  float var = (red[0] + red[1] + red[2] + red[3]) * (1.0f / 1024.0f);
  float rstd = 1.0f / sqrtf(var + 1e-5f);
  float4 gv = *(const float4*)&gamma[tid * 4];
  float4 bv = *(const float4*)&beta[tid * 4];
  float hv4[4] = {d0 * rstd * gv.x + bv.x, d1 * rstd * gv.y + bv.y,
                  d2 * rstd * gv.z + bv.z, d3 * rstd * gv.w + bv.w};
  {  // write h row (bf16) into the first half of this t row; all threads
     // loaded their t chunk before the first barrier -> in-place safe.
    short4v hb;
    for (int u = 0; u < 4; u++) hb[u] = (short)f2bf(scrub(hv4[u]));
    *(short4v*)&t16[(size_t)tok * 2048 + tid * 4] = hb;
  }
  float p[8] = {};
  for (int u = 0; u < 4; u++) {
    int j = tid * 4 + u;
    float4 w0 = *(const float4*)&Wg[(size_t)j * 8];
    float4 w1 = *(const float4*)&Wg[(size_t)j * 8 + 4];
    p[0] += hv4[u] * w0.x; p[1] += hv4[u] * w0.y;
    p[2] += hv4[u] * w0.z; p[3] += hv4[u] * w0.w;
    p[4] += hv4[u] * w1.x; p[5] += hv4[u] * w1.y;
    p[6] += hv4[u] * w1.z; p[7] += hv4[u] * w1.w;
  }
  for (int e = 0; e < 8; e++)
    for (int off = 32; off; off >>= 1) p[e] += __shfl_down(p[e], off, 64);
  if (lane == 0)
    for (int e = 0; e < 8; e++) rg[wv][e] = p[e];
  __syncthreads();
  if (tid == 0) {
    float lg[8];
    for (int e = 0; e < 8; e++) lg[e] = rg[0][e] + rg[1][e] + rg[2][e] + rg[3][e];
    int best = 0; float bm = lg[0];
    for (int e = 1; e < 8; e++) if (lg[e] > bm) { bm = lg[e]; best = e; } // first-index ties
    float se = 0.f;
    for (int e = 0; e < 8; e++) se += expf(lg[e] - bm);
    gate[tok] = scrub(1.0f / se);
    int pos = atomicAdd(&cnt[best], 1);
    idx[best * NTOK + pos] = tok;
  }
}

// ---------------- grouped MoE GEMM, 1-pass bf16, 128x128 tiles, BK=64.
// Block-index remap: d = y + 8m + 160z -> all m-blocks of panel (y,z) share
// disp%8 (one XCD's L2 per B panel). A = h16 rows; B = we16 rows.
__global__ __launch_bounds__(256) void moe_gemm(
    const u16* __restrict__ t16, const float* __restrict__ be,
    const float* __restrict__ gate, const int* __restrict__ idx,
    const int* __restrict__ cnt, float* __restrict__ out) {
  const int d = blockIdx.x + 20 * blockIdx.y + 160 * blockIdx.z;
  const int y = d & 7, r2 = d >> 3;
  const int m = r2 % 20, e = r2 / 20;
  const int count = cnt[e];
  const int m0 = m * 128, n0 = y * 128;
  if (m0 >= count) return;
  const int* eidx = idx + e * NTOK;
  __shared__ u16 As[128][72], Bs[128][72];  // BK=64 + pad (144 B stride)
  const int tid = threadIdx.x, lane = tid & 63, wv = tid >> 6;
  const int wm = (wv >> 1) * 64, wn = (wv & 1) * 64;
  const int quad = lane >> 4, l15 = lane & 15;
  const int sr = tid >> 1, sc = (tid & 1) * 32;
  const int rrow = m0 + sr;
  const int tokr_s = (rrow < count) ? eidx[rrow] : 0;
  const u16* aB = t16 + (size_t)tokr_s * 2048 + sc;
  const u16* bB = t16 + ((size_t)(e * 1024 + n0 + sr)) * 2048 + 1024 + sc;
  f32x4 acc[4][4] = {};
  short8 R0[8], R1[8];
#define MLOAD(R, KK) { \
  R[0] = *(const short8*)(aB + (KK));      R[1] = *(const short8*)(aB + (KK) + 8); \
  R[2] = *(const short8*)(aB + (KK) + 16); R[3] = *(const short8*)(aB + (KK) + 24); \
  R[4] = *(const short8*)(bB + (KK));      R[5] = *(const short8*)(bB + (KK) + 8); \
  R[6] = *(const short8*)(bB + (KK) + 16); R[7] = *(const short8*)(bB + (KK) + 24); }
#define MSTAGE(R) { \
  *(short8*)&As[sr][sc]      = R[0]; *(short8*)&As[sr][sc + 8]  = R[1]; \
  *(short8*)&As[sr][sc + 16] = R[2]; *(short8*)&As[sr][sc + 24] = R[3]; \
  *(short8*)&Bs[sr][sc]      = R[4]; *(short8*)&Bs[sr][sc + 8]  = R[5]; \
  *(short8*)&Bs[sr][sc + 16] = R[6]; *(short8*)&Bs[sr][sc + 24] = R[7]; }
#define MCOMPUTE() { \
  _Pragma("unroll") \
  for (int ks = 0; ks < 2; ks++) { \
    short8 af[4], bfr[4]; \
    _Pragma("unroll") \
    for (int i = 0; i < 4; i++) af[i] = *(const short8*)&As[wm + 16 * i + l15][ks * 32 + quad * 8]; \
    _Pragma("unroll") \
    for (int j = 0; j < 4; j++) bfr[j] = *(const short8*)&Bs[wn + 16 * j + l15][ks * 32 + quad * 8]; \
    _Pragma("unroll") \
    for (int i = 0; i < 4; i++) \
      _Pragma("unroll") \
      for (int j = 0; j < 4; j++) \
        acc[i][j] = __builtin_amdgcn_mfma_f32_16x16x32_bf16(af[i], bfr[j], acc[i][j], 0, 0, 0); \
  } }
  MLOAD(R0, 0);
  for (int k0 = 0; k0 < KD; k0 += 128) {
    MSTAGE(R0);
    MLOAD(R1, k0 + 64);
    __syncthreads();
    MCOMPUTE();
    __syncthreads();
    MSTAGE(R1);
    if (k0 + 128 < KD) MLOAD(R0, k0 + 128);
    __syncthreads();
    MCOMPUTE();
    __syncthreads();
  }
#undef MLOAD
#undef MSTAGE
#undef MCOMPUTE
  for (int i = 0; i < 4; i++)
    for (int r = 0; r < 4; r++) {
      int lm = m0 + wm + 16 * i + quad * 4 + r;
      if (lm < count) {
        int tokr = eidx[lm];
        float g = gate[tokr];
        for (int j = 0; j < 4; j++) {
          int n = n0 + wn + 16 * j + l15;
          out[(size_t)tokr * KD + n] = scrub(g * (acc[i][j][r] + be[e * KD + n]));
        }
      }
    }
}

extern "C" void kernel_launch(void* const* d_in, const int* in_sizes, int n_in,
                              void* d_out, int out_size, void* d_ws, size_t ws_size,
                              hipStream_t stream) {
  const float* x     = (const float*)d_in[0];
  const float* Wq    = (const float*)d_in[1];
  const float* bq    = (const float*)d_in[2];
  const float* Wk    = (const float*)d_in[3];
  const float* bk    = (const float*)d_in[4];
  const float* Wv    = (const float*)d_in[5];
  const float* bv    = (const float*)d_in[6];
  const float* Wo    = (const float*)d_in[7];
  const float* bo    = (const float*)d_in[8];
  const float* gamma = (const float*)d_in[9];
  const float* beta  = (const float*)d_in[10];
  const float* Wg    = (const float*)d_in[11];
  const float* We    = (const float*)d_in[12];
  const float* be    = (const float*)d_in[13];
  float* out = (float*)d_out;
  char* ws = (char*)d_ws;

  // ---- layout, peak exactly 40,239,104 B (== proven peak) ----
  // [0, 393216):          gate | idx | cnt
  // phase 1 (slab loop, serial qkv->attn):
  //   [393216, 19267584):   Wq/Wk/Wv split planes (9 x 2 MB)
  //   [19267584, 29753344): k slab (2560 rows x 4 KB)
  //   [29753344, 40239104): v slab
  //   q slabs live in d_out rows (attn overwrites them in-place with o)
  // phase 2 (wo..moe):
  //   [393216, 33947648):  t (8192 x 4 KB) over dead planes/slabs
  //     h16 = first 2 KB of each t row; we16 = second 2 KB
  //   [33947648, 40239104): Wo split planes (prepped after slab loop)
  const size_t GATE_OFF = 0;
  const size_t IDX_OFF  = 32768;
  const size_t CNT_OFF  = IDX_OFF + (size_t)8 * NTOK * 4;
  const size_t WQKV_OFF = 393216;
  const size_t K_OFF    = WQKV_OFF + (size_t)9 * 1048576 * 2;  // 19267584
  const size_t V_OFF    = K_OFF + (size_t)SLAB * KD * 4;       // 29753344
  const size_t T_OFF    = 393216;
  const size_t WOP_OFF  = T_OFF + (size_t)NTOK * KD * 4;       // 33947648

  float* gate = (float*)(ws + GATE_OFF);
  int*   idx  = (int*)(ws + IDX_OFF);
  int*   cnt  = (int*)(ws + CNT_OFF);
  u16*   wqkv = (u16*)(ws + WQKV_OFF);
  float* kbuf = (float*)(ws + K_OFF);
  float* vbuf = (float*)(ws + V_OFF);
  float* t    = (float*)(ws + T_OFF);
  u16*   t16  = (u16*)(ws + T_OFF);
  u16*   wop  = (u16*)(ws + WOP_OFF);

  (void)hipMemsetAsync(cnt, 0, 8 * sizeof(int), stream);
  prep_w<<<dim3(16, 16, 3), 256, 0, stream>>>(Wq, Wk, Wv, Wo, wqkv, wop, 0);

  // slabs: 2560, 2560, 2560, 512
  for (int tok0 = 0; tok0 < NTOK; tok0 += SLAB) {
    const int len = (NTOK - tok0 < SLAB) ? (NTOK - tok0) : SLAB;
    qkv_gemm<<<dim3(len / 128, 8, 3), 256, 0, stream>>>(
        x, wqkv, bq, bk, bv, out + (size_t)tok0 * KD, kbuf, vbuf, tok0);
    attn_fp32<<<dim3(len / 64 * 16), 256, 0, stream>>>(
        out + (size_t)tok0 * KD, kbuf, vbuf);
  }

  prep_w<<<dim3(16, 16, 1), 256, 0, stream>>>(Wq, Wk, Wv, Wo, wqkv, wop, 3);
  wo_gemm<<<dim3(NTOK / 128, 8), 256, 0, stream>>>(out, wop, bo, x, t);
  ln_gate<<<dim3(NTOK), 256, 0, stream>>>(t, gamma, beta, Wg, gate, idx, cnt, t16);
  prep_we<<<dim3(16, 16, 8), 256, 0, stream>>>(We, t16);
  // counts ~ Binomial(8192, 1/8) -> max ~1024+-30; 20 m-blocks covers 2560.
  moe_gemm<<<dim3(20, 8, 8), 256, 0, stream>>>(t16, be, gate, idx, cnt, out);
}

// Round 10
// 783.179 us; speedup vs baseline: 1.0888x; 1.0888x over previous
//
#include <hip/hip_runtime.h>

// MoE Transformer block, MI355X/gfx950. B=2,S=4096,D=1024,H=16,BS=64,E=8,HD=64.
//
// ALL INPUTS/OUTPUT ARE FP32. Gating argmax needs ~1e-6 logit fidelity, so
// QKV and Wo GEMMs use EXACT 3-way bf16 splits with 6 MFMA passes. Attention
// is pure fp32 VALU. MoE GEMM is 1-pass bf16.
//
// R17 (moe locality; all other kernels frozen at R16):
//  - moe block decode t=L&7,s=L>>3,m=s>>3,y=s&7,e=(t-m)&7: all 8 y-blocks of
//    an (m,e) pair share L%8 -> one XCD's L2 gathers those A rows once and
//    serves them 8x. (R16's remap had encode!=decode -> scrambled, untested.)
//  - sorted per-expert idx via 1-block counting sort (ln_gate writes best[],
//    no atomics): the cold A-gather becomes ascending-address. Within-expert
//    permutation doesn't change per-token math -> bit-identical.

typedef unsigned short u16;
typedef __attribute__((ext_vector_type(8))) short short8;
typedef __attribute__((ext_vector_type(4))) short short4v;
typedef __attribute__((ext_vector_type(4))) float f32x4;

static constexpr int KD = 1024;
static constexpr int NTOK = 8192;
static constexpr int SLAB = 2560;   // 20 x 128; slabs 2560,2560,2560,512

__device__ inline u16 f2bf(float x) {
  union { float f; unsigned u; } c; c.f = x;
  unsigned r = c.u + 0x7fffu + ((c.u >> 16) & 1u);
  return (u16)(r >> 16);
}
__device__ inline float bf2f(u16 b) {
  union { unsigned u; float f; } c; c.u = ((unsigned)b) << 16; return c.f;
}
__device__ inline float scrub(float x) {   // finite -> x, else 0
  return (x == x && fabsf(x) < 1e30f) ? x : 0.0f;
}
struct Split3 { short h, m, l; };
__device__ inline Split3 split3(float a) {
  Split3 s;
  u16 hb = f2bf(a); float r1 = a - bf2f(hb);   // exact
  u16 mb = f2bf(r1); float r2 = r1 - bf2f(mb); // exact
  s.h = (short)hb; s.m = (short)mb; s.l = (short)f2bf(r2);
  return s;
}

// ---------------- one-time: W[k][n] fp32 -> planes [n][k] bf16 (split3)
// z = blockIdx.z + z_base: 0..2 -> wqkv plane sets, 3 -> wo plane set.
__global__ __launch_bounds__(256) void prep_w(
    const float* __restrict__ Wq, const float* __restrict__ Wk,
    const float* __restrict__ Wv, const float* __restrict__ Wo,
    u16* __restrict__ wqkv, u16* __restrict__ wop, int z_base) {
  const int z = blockIdx.z + z_base;
  const float* W = z == 0 ? Wq : z == 1 ? Wk : z == 2 ? Wv : Wo;
  u16* ph_ = (z < 3) ? (wqkv + (size_t)z * 3145728) : wop;
  u16* pm_ = ph_ + 1048576;
  u16* pl_ = pm_ + 1048576;
  const int k0 = blockIdx.x * 64, n0 = blockIdx.y * 64;
  __shared__ u16 Th[64][80], Tm[64][80], Tl[64][80];
  const int tid = threadIdx.x;
  {
    const int r = tid >> 2, c0 = (tid & 3) * 16;
    const float* wp = &W[(size_t)(k0 + r) * KD + n0 + c0];
    for (int u = 0; u < 16; u++) {
      Split3 s = split3(wp[u]);
      Th[c0 + u][r] = (u16)s.h; Tm[c0 + u][r] = (u16)s.m; Tl[c0 + u][r] = (u16)s.l;
    }
  }
  __syncthreads();
  {
    const int n = tid >> 2, kc = (tid & 3) * 16;
    size_t off = (size_t)(n0 + n) * KD + k0 + kc;
    *(short8*)&ph_[off]     = *(const short8*)&Th[n][kc];
    *(short8*)&ph_[off + 8] = *(const short8*)&Th[n][kc + 8];
    *(short8*)&pm_[off]     = *(const short8*)&Tm[n][kc];
    *(short8*)&pm_[off + 8] = *(const short8*)&Tm[n][kc + 8];
    *(short8*)&pl_[off]     = *(const short8*)&Tl[n][kc];
    *(short8*)&pl_[off + 8] = *(const short8*)&Tl[n][kc + 8];
  }
}

// ---------------- one-time: We[e][k][n] fp32 -> bf16 [e*1024+n] rows, stored
// in the SECOND half (u16 offset row*2048+1024) of each t row (after ln_gate).
__global__ __launch_bounds__(256) void prep_we(
    const float* __restrict__ We, u16* __restrict__ t16) {
  const int e = blockIdx.z;
  const int k0 = blockIdx.x * 64, n0 = blockIdx.y * 64;
  __shared__ u16 T[64][80];
  const int tid = threadIdx.x;
  {
    const int r = tid >> 2, c0 = (tid & 3) * 16;
    const float* wp = &We[((size_t)e * KD + k0 + r) * KD + n0 + c0];
    for (int u = 0; u < 16; u++) T[c0 + u][r] = f2bf(wp[u]);
  }
  __syncthreads();
  {
    const int n = tid >> 2, kc = (tid & 3) * 16;
    size_t off = ((size_t)(e * 1024 + n0 + n)) * 2048 + 1024 + k0 + kc;
    *(short8*)&t16[off]     = *(const short8*)&T[n][kc];
    *(short8*)&t16[off + 8] = *(const short8*)&T[n][kc + 8];
  }
}

// ---------------- shared pieces for the 128x128 6-pass split GEMMs ----------
__device__ inline void qload(const float* aB, const u16* bBh, const u16* bBm,
                             const u16* bBl, int kk, f32x4* A, short8* B) {
#pragma unroll
  for (int u = 0; u < 4; u++) A[u] = *(const f32x4*)(aB + kk + 4 * u);
  B[0] = *(const short8*)(bBh + kk); B[1] = *(const short8*)(bBh + kk + 8);
  B[2] = *(const short8*)(bBm + kk); B[3] = *(const short8*)(bBm + kk + 8);
  B[4] = *(const short8*)(bBl + kk); B[5] = *(const short8*)(bBl + kk + 8);
}

__device__ inline void qstage(const f32x4* A, const short8* B,
    u16 (*Ah)[40], u16 (*Am)[40], u16 (*Al)[40],
    u16 (*Bh)[40], u16 (*Bm)[40], u16 (*Bl)[40], int sr, int sc) {
  short8 h0, h1, mm0, mm1, l0, l1;
#pragma unroll
  for (int u = 0; u < 8; u++) {
    Split3 s = split3(A[u >> 2][u & 3]);
    h0[u] = s.h; mm0[u] = s.m; l0[u] = s.l;
  }
#pragma unroll
  for (int u = 0; u < 8; u++) {
    Split3 s = split3(A[2 + (u >> 2)][u & 3]);
    h1[u] = s.h; mm1[u] = s.m; l1[u] = s.l;
  }
  *(short8*)&Ah[sr][sc] = h0;  *(short8*)&Ah[sr][sc + 8] = h1;
  *(short8*)&Am[sr][sc] = mm0; *(short8*)&Am[sr][sc + 8] = mm1;
  *(short8*)&Al[sr][sc] = l0;  *(short8*)&Al[sr][sc + 8] = l1;
  *(short8*)&Bh[sr][sc] = B[0]; *(short8*)&Bh[sr][sc + 8] = B[1];
  *(short8*)&Bm[sr][sc] = B[2]; *(short8*)&Bm[sr][sc + 8] = B[3];
  *(short8*)&Bl[sr][sc] = B[4]; *(short8*)&Bl[sr][sc + 8] = B[5];
}

__device__ inline void qcompute(
    const u16 (*Ah)[40], const u16 (*Am)[40], const u16 (*Al)[40],
    const u16 (*Bh)[40], const u16 (*Bm)[40], const u16 (*Bl)[40],
    int wm, int wn, int quad, int l15, f32x4 (*acc)[4]) {
  short8 ah[4], am[4], al[4];
#pragma unroll
  for (int i = 0; i < 4; i++) {
    ah[i] = *(const short8*)&Ah[wm + 16 * i + l15][quad * 8];
    am[i] = *(const short8*)&Am[wm + 16 * i + l15][quad * 8];
    al[i] = *(const short8*)&Al[wm + 16 * i + l15][quad * 8];
  }
#pragma unroll
  for (int j = 0; j < 4; j++) {
    short8 bh = *(const short8*)&Bh[wn + 16 * j + l15][quad * 8];
    short8 bm = *(const short8*)&Bm[wn + 16 * j + l15][quad * 8];
    short8 bl = *(const short8*)&Bl[wn + 16 * j + l15][quad * 8];
#pragma unroll
    for (int i = 0; i < 4; i++) {
      f32x4 a = acc[i][j];
      a = __builtin_amdgcn_mfma_f32_16x16x32_bf16(al[i], bh, a, 0, 0, 0);
      a = __builtin_amdgcn_mfma_f32_16x16x32_bf16(am[i], bm, a, 0, 0, 0);
      a = __builtin_amdgcn_mfma_f32_16x16x32_bf16(ah[i], bl, a, 0, 0, 0);
      a = __builtin_amdgcn_mfma_f32_16x16x32_bf16(am[i], bh, a, 0, 0, 0);
      a = __builtin_amdgcn_mfma_f32_16x16x32_bf16(ah[i], bm, a, 0, 0, 0);
      a = __builtin_amdgcn_mfma_f32_16x16x32_bf16(ah[i], bh, a, 0, 0, 0);
      acc[i][j] = a;
    }
  }
}

// ---------------- fused QKV GEMM (slab), 128x128 tile, 6-pass, prefetched.
// q -> d_out rows of this slab; k,v -> workspace slab buffers.
__global__ __launch_bounds__(256, 2) void qkv_gemm(
    const float* __restrict__ x, const u16* __restrict__ wt,
    const float* __restrict__ bq, const float* __restrict__ bk,
    const float* __restrict__ bv,
    float* __restrict__ qo, float* __restrict__ ko, float* __restrict__ vo,
    int tok0) {
  const int m0 = blockIdx.x * 128, n0 = blockIdx.y * 128, z = blockIdx.z;
  const u16* Wh = wt + (size_t)z * 3145728;
  const u16* Wm = Wh + 1048576;
  const u16* Wl = Wm + 1048576;
  const float* bias = z == 0 ? bq : z == 1 ? bk : bv;
  float* outp = z == 0 ? qo : z == 1 ? ko : vo;
  __shared__ u16 Ah[128][40], Am[128][40], Al[128][40];
  __shared__ u16 Bh[128][40], Bm[128][40], Bl[128][40];
  const int tid = threadIdx.x, lane = tid & 63, wv = tid >> 6;
  const int wm = (wv >> 1) * 64, wn = (wv & 1) * 64;
  const int quad = lane >> 4, l15 = lane & 15;
  const int sr = tid >> 1, sc = (tid & 1) * 16;
  const float* aB = &x[(size_t)(tok0 + m0 + sr) * KD + sc];
  const u16* bBh = &Wh[(size_t)(n0 + sr) * KD + sc];
  const u16* bBm = &Wm[(size_t)(n0 + sr) * KD + sc];
  const u16* bBl = &Wl[(size_t)(n0 + sr) * KD + sc];
  f32x4 acc[4][4] = {};
  f32x4 A0[4], A1[4]; short8 B0[6], B1[6];
  qload(aB, bBh, bBm, bBl, 0, A0, B0);
  for (int k0 = 0; k0 < KD; k0 += 64) {
    qstage(A0, B0, Ah, Am, Al, Bh, Bm, Bl, sr, sc);
    qload(aB, bBh, bBm, bBl, k0 + 32, A1, B1);
    __syncthreads();
    qcompute(Ah, Am, Al, Bh, Bm, Bl, wm, wn, quad, l15, acc);
    __syncthreads();
    qstage(A1, B1, Ah, Am, Al, Bh, Bm, Bl, sr, sc);
    if (k0 + 64 < KD) qload(aB, bBh, bBm, bBl, k0 + 64, A0, B0);
    __syncthreads();
    qcompute(Ah, Am, Al, Bh, Bm, Bl, wm, wn, quad, l15, acc);
    __syncthreads();
  }
  for (int j = 0; j < 4; j++) {
    int n = n0 + wn + 16 * j + l15;
    float bb = bias[n];
    for (int i = 0; i < 4; i++) {
      int mb = m0 + wm + 16 * i + quad * 4;
      for (int r = 0; r < 4; r++)
        outp[(size_t)(mb + r) * KD + n] = scrub(acc[i][j][r] + bb);
    }
  }
}

// ---------------- block-local attention, fp32 VALU; o in-place over q rows.
// kj = part + 4*j (conflict-free); d-outer QK loop.
__global__ __launch_bounds__(256) void attn_fp32(
    float* __restrict__ q, const float* __restrict__ k,
    const float* __restrict__ v) {
  const int nb = blockIdx.x >> 4, h = blockIdx.x & 15;
  const size_t base = (size_t)(nb * 64) * KD + h * 64;
  __shared__ float Qs[64][68], Ks[64][68], Vs[64][68];
  const int tid = threadIdx.x;
  {
    const int r = tid >> 2, c0 = (tid & 3) * 16;
    const float* qp = &q[base + (size_t)r * KD + c0];
    const float* kp = &k[base + (size_t)r * KD + c0];
    const float* vp = &v[base + (size_t)r * KD + c0];
    for (int u = 0; u < 16; u += 4) {
      *(float4*)&Qs[r][c0 + u] = *(const float4*)(qp + u);
      *(float4*)&Ks[r][c0 + u] = *(const float4*)(kp + u);
      *(float4*)&Vs[r][c0 + u] = *(const float4*)(vp + u);
    }
  }
  __syncthreads();
  const int qi = tid >> 2, part = tid & 3;
  float sc[16];
#pragma unroll
  for (int j = 0; j < 16; j++) sc[j] = 0.f;
  for (int d = 0; d < 64; d += 4) {
    float4 qv = *(const float4*)&Qs[qi][d];
#pragma unroll
    for (int j = 0; j < 16; j++) {
      const int kj = part + 4 * j;
      float4 kv = *(const float4*)&Ks[kj][d];
      sc[j] += qv.x * kv.x + qv.y * kv.y + qv.z * kv.z + qv.w * kv.w;
    }
  }
#pragma unroll
  for (int j = 0; j < 16; j++) sc[j] *= 0.125f;
  float mx = sc[0];
  for (int j = 1; j < 16; j++) mx = fmaxf(mx, sc[j]);
  mx = fmaxf(mx, __shfl_xor(mx, 1, 64));
  mx = fmaxf(mx, __shfl_xor(mx, 2, 64));
  float sum = 0.f;
  for (int j = 0; j < 16; j++) { sc[j] = expf(sc[j] - mx); sum += sc[j]; }
  sum += __shfl_xor(sum, 1, 64);
  sum += __shfl_xor(sum, 2, 64);
  const float inv = 1.0f / sum;
  float po[64];
  for (int d = 0; d < 64; d++) po[d] = 0.f;
  for (int j = 0; j < 16; j++) {
    const float pv = sc[j] * inv;
    const int kj = part + 4 * j;
    for (int d = 0; d < 64; d += 4) {
      float4 vv = *(const float4*)&Vs[kj][d];
      po[d]     += pv * vv.x; po[d + 1] += pv * vv.y;
      po[d + 2] += pv * vv.z; po[d + 3] += pv * vv.w;
    }
  }
  for (int d = 0; d < 64; d++) {
    po[d] += __shfl_xor(po[d], 1, 64);
    po[d] += __shfl_xor(po[d], 2, 64);
  }
#pragma unroll
  for (int d0 = 0; d0 < 64; d0 += 16)
    if ((d0 >> 4) == part) {
#pragma unroll
      for (int u = 0; u < 16; u += 4) {
        float4 st; st.x = scrub(po[d0 + u]);     st.y = scrub(po[d0 + u + 1]);
                   st.z = scrub(po[d0 + u + 2]); st.w = scrub(po[d0 + u + 3]);
        *(float4*)&q[base + (size_t)qi * KD + d0 + u] = st;
      }
    }
}

// ---------------- Wo GEMM (full-token), 6-pass split-bf16: t = o @ Wo + bo + x
__global__ __launch_bounds__(256, 2) void wo_gemm(
    const float* __restrict__ o, const u16* __restrict__ wto,
    const float* __restrict__ bo, const float* __restrict__ xin,
    float* __restrict__ t) {
  const int m0 = blockIdx.x * 128, n0 = blockIdx.y * 128;
  const u16* Wh = wto;
  const u16* Wm = Wh + 1048576;
  const u16* Wl = Wm + 1048576;
  __shared__ u16 Ah[128][40], Am[128][40], Al[128][40];
  __shared__ u16 Bh[128][40], Bm[128][40], Bl[128][40];
  const int tid = threadIdx.x, lane = tid & 63, wv = tid >> 6;
  const int wm = (wv >> 1) * 64, wn = (wv & 1) * 64;
  const int quad = lane >> 4, l15 = lane & 15;
  const int sr = tid >> 1, sc = (tid & 1) * 16;
  const float* aB = &o[(size_t)(m0 + sr) * KD + sc];
  const u16* bBh = &Wh[(size_t)(n0 + sr) * KD + sc];
  const u16* bBm = &Wm[(size_t)(n0 + sr) * KD + sc];
  const u16* bBl = &Wl[(size_t)(n0 + sr) * KD + sc];
  f32x4 acc[4][4] = {};
  f32x4 A0[4], A1[4]; short8 B0[6], B1[6];
  qload(aB, bBh, bBm, bBl, 0, A0, B0);
  for (int k0 = 0; k0 < KD; k0 += 64) {
    qstage(A0, B0, Ah, Am, Al, Bh, Bm, Bl, sr, sc);
    qload(aB, bBh, bBm, bBl, k0 + 32, A1, B1);
    __syncthreads();
    qcompute(Ah, Am, Al, Bh, Bm, Bl, wm, wn, quad, l15, acc);
    __syncthreads();
    qstage(A1, B1, Ah, Am, Al, Bh, Bm, Bl, sr, sc);
    if (k0 + 64 < KD) qload(aB, bBh, bBm, bBl, k0 + 64, A0, B0);
    __syncthreads();
    qcompute(Ah, Am, Al, Bh, Bm, Bl, wm, wn, quad, l15, acc);
    __syncthreads();
  }
  for (int j = 0; j < 4; j++) {
    int n = n0 + wn + 16 * j + l15;
    float bb = bo[n];
    for (int i = 0; i < 4; i++) {
      int mb = m0 + wm + 16 * i + quad * 4;
      for (int r = 0; r < 4; r++) {
        size_t off = (size_t)(mb + r) * KD + n;
        t[off] = scrub(acc[i][j][r] + bb + xin[off]);
      }
    }
  }
}

// ---------------- LayerNorm + gating; h16 in-place over t rows; best[] out
__global__ __launch_bounds__(256) void ln_gate(
    const float* __restrict__ t, const float* __restrict__ gamma,
    const float* __restrict__ beta, const float* __restrict__ Wg,
    float* __restrict__ gate, int* __restrict__ beste,
    u16* __restrict__ t16) {
  const int tok = blockIdx.x;
  const int tid = threadIdx.x, lane = tid & 63, wv = tid >> 6;
  const float* row = t + (size_t)tok * KD;
  float4 xv = *(const float4*)&row[tid * 4];
  __shared__ float red[4];
  __shared__ float rg[4][8];
  float s = xv.x + xv.y + xv.z + xv.w;
  for (int off = 32; off; off >>= 1) s += __shfl_down(s, off, 64);
  if (lane == 0) red[wv] = s;
  __syncthreads();
  float mu = (red[0] + red[1] + red[2] + red[3]) * (1.0f / 1024.0f);
  __syncthreads();
  float d0 = xv.x - mu, d1 = xv.y - mu, d2 = xv.z - mu, d3 = xv.w - mu;
  float ss = d0 * d0 + d1 * d1 + d2 * d2 + d3 * d3;
  for (int off = 32; off; off >>= 1) ss += __shfl_down(ss, off, 64);
  if (lane == 0) red[wv] = ss;
  __syncthreads();
  float var = (red[0] + red[1] + red[2] + red[3]) * (1.0f / 1024.0f);
  float rstd = 1.0f / sqrtf(var + 1e-5f);
  float4 gv = *(const float4*)&gamma[tid * 4];
  float4 bv = *(const float4*)&beta[tid * 4];
  float hv4[4] = {d0 * rstd * gv.x + bv.x, d1 * rstd * gv.y + bv.y,
                  d2 * rstd * gv.z + bv.z, d3 * rstd * gv.w + bv.w};
  {  // write h row (bf16) into the first half of this t row; all threads
     // loaded their t chunk before the first barrier -> in-place safe.
    short4v hb;
    for (int u = 0; u < 4; u++) hb[u] = (short)f2bf(scrub(hv4[u]));
    *(short4v*)&t16[(size_t)tok * 2048 + tid * 4] = hb;
  }
  float p[8] = {};
  for (int u = 0; u < 4; u++) {
    int j = tid * 4 + u;
    float4 w0 = *(const float4*)&Wg[(size_t)j * 8];
    float4 w1 = *(const float4*)&Wg[(size_t)j * 8 + 4];
    p[0] += hv4[u] * w0.x; p[1] += hv4[u] * w0.y;
    p[2] += hv4[u] * w0.z; p[3] += hv4[u] * w0.w;
    p[4] += hv4[u] * w1.x; p[5] += hv4[u] * w1.y;
    p[6] += hv4[u] * w1.z; p[7] += hv4[u] * w1.w;
  }
  for (int e = 0; e < 8; e++)
    for (int off = 32; off; off >>= 1) p[e] += __shfl_down(p[e], off, 64);
  if (lane == 0)
    for (int e = 0; e < 8; e++) rg[wv][e] = p[e];
  __syncthreads();
  if (tid == 0) {
    float lg[8];
    for (int e = 0; e < 8; e++) lg[e] = rg[0][e] + rg[1][e] + rg[2][e] + rg[3][e];
    int best = 0; float bm = lg[0];
    for (int e = 1; e < 8; e++) if (lg[e] > bm) { bm = lg[e]; best = e; } // first-index ties
    float se = 0.f;
    for (int e = 0; e < 8; e++) se += expf(lg[e] - bm);
    gate[tok] = scrub(1.0f / se);
    beste[tok] = best;
  }
}

// ---------------- counting sort: best[] -> per-expert idx (ascending token
// order) + cnt. One block, 256 threads, chunk = 32 tokens/thread.
__global__ __launch_bounds__(256) void bucket_sort(
    const int* __restrict__ best, int* __restrict__ idx, int* __restrict__ cnt) {
  __shared__ int hist[256][8];
  const int tid = threadIdx.x;
  for (int e = 0; e < 8; e++) hist[tid][e] = 0;
  for (int i = 0; i < 32; i++) hist[tid][best[tid * 32 + i]]++;
  __syncthreads();
  if (tid < 8) {  // exclusive prefix over chunks for expert `tid`
    int s = 0;
    for (int i = 0; i < 256; i++) { int v = hist[i][tid]; hist[i][tid] = s; s += v; }
    cnt[tid] = s;
  }
  __syncthreads();
  for (int i = 0; i < 32; i++) {
    int to = tid * 32 + i;
    int e = best[to];
    int p = hist[tid][e]++;
    idx[e * NTOK + p] = to;
  }
}

// ---------------- grouped MoE GEMM, 1-pass bf16, 128x128 tiles, BK=64.
// XCD-stable decode: t=L&7, s=L>>3, m=s>>3, y=s&7, e=(t-m)&7 -> all 8
// y-blocks of (m,e) share L%8 (one XCD gathers those A rows once).
__global__ __launch_bounds__(256) void moe_gemm(
    const u16* __restrict__ t16, const float* __restrict__ be,
    const float* __restrict__ gate, const int* __restrict__ idx,
    const int* __restrict__ cnt, float* __restrict__ out) {
  const int L = blockIdx.x;
  const int xcd = L & 7, s = L >> 3;
  const int m = s >> 3, y = s & 7;
  const int e = (xcd - m + 24) & 7;
  const int count = cnt[e];
  const int m0 = m * 128, n0 = y * 128;
  if (m0 >= count) return;
  const int* eidx = idx + e * NTOK;
  __shared__ u16 As[128][72], Bs[128][72];  // BK=64 + pad (144 B stride)
  const int tid = threadIdx.x, lane = tid & 63, wv = tid >> 6;
  const int wm = (wv >> 1) * 64, wn = (wv & 1) * 64;
  const int quad = lane >> 4, l15 = lane & 15;
  const int sr = tid >> 1, sc = (tid & 1) * 32;
  const int rrow = m0 + sr;
  const int tokr_s = (rrow < count) ? eidx[rrow] : 0;
  const u16* aB = t16 + (size_t)tokr_s * 2048 + sc;
  const u16* bB = t16 + ((size_t)(e * 1024 + n0 + sr)) * 2048 + 1024 + sc;
  f32x4 acc[4][4] = {};
  short8 R0[8], R1[8];
#define MLOAD(R, KK) { \
  R[0] = *(const short8*)(aB + (KK));      R[1] = *(const short8*)(aB + (KK) + 8); \
  R[2] = *(const short8*)(aB + (KK) + 16); R[3] = *(const short8*)(aB + (KK) + 24); \
  R[4] = *(const short8*)(bB + (KK));      R[5] = *(const short8*)(bB + (KK) + 8); \
  R[6] = *(const short8*)(bB + (KK) + 16); R[7] = *(const short8*)(bB + (KK) + 24); }
#define MSTAGE(R) { \
  *(short8*)&As[sr][sc]      = R[0]; *(short8*)&As[sr][sc + 8]  = R[1]; \
  *(short8*)&As[sr][sc + 16] = R[2]; *(short8*)&As[sr][sc + 24] = R[3]; \
  *(short8*)&Bs[sr][sc]      = R[4]; *(short8*)&Bs[sr][sc + 8]  = R[5]; \
  *(short8*)&Bs[sr][sc + 16] = R[6]; *(short8*)&Bs[sr][sc + 24] = R[7]; }
#define MCOMPUTE() { \
  _Pragma("unroll") \
  for (int ks = 0; ks < 2; ks++) { \
    short8 af[4], bfr[4]; \
    _Pragma("unroll") \
    for (int i = 0; i < 4; i++) af[i] = *(const short8*)&As[wm + 16 * i + l15][ks * 32 + quad * 8]; \
    _Pragma("unroll") \
    for (int j = 0; j < 4; j++) bfr[j] = *(const short8*)&Bs[wn + 16 * j + l15][ks * 32 + quad * 8]; \
    _Pragma("unroll") \
    for (int i = 0; i < 4; i++) \
      _Pragma("unroll") \
      for (int j = 0; j < 4; j++) \
        acc[i][j] = __builtin_amdgcn_mfma_f32_16x16x32_bf16(af[i], bfr[j], acc[i][j], 0, 0, 0); \
  } }
  MLOAD(R0, 0);
  for (int k0 = 0; k0 < KD; k0 += 128) {
    MSTAGE(R0);
    MLOAD(R1, k0 + 64);
    __syncthreads();
    MCOMPUTE();
    __syncthreads();
    MSTAGE(R1);
    if (k0 + 128 < KD) MLOAD(R0, k0 + 128);
    __syncthreads();
    MCOMPUTE();
    __syncthreads();
  }
#undef MLOAD
#undef MSTAGE
#undef MCOMPUTE
  for (int i = 0; i < 4; i++)
    for (int r = 0; r < 4; r++) {
      int lm = m0 + wm + 16 * i + quad * 4 + r;
      if (lm < count) {
        int tokr = eidx[lm];
        float g = gate[tokr];
        for (int j = 0; j < 4; j++) {
          int n = n0 + wn + 16 * j + l15;
          out[(size_t)tokr * KD + n] = scrub(g * (acc[i][j][r] + be[e * KD + n]));
        }
      }
    }
}

extern "C" void kernel_launch(void* const* d_in, const int* in_sizes, int n_in,
                              void* d_out, int out_size, void* d_ws, size_t ws_size,
                              hipStream_t stream) {
  const float* x     = (const float*)d_in[0];
  const float* Wq    = (const float*)d_in[1];
  const float* bq    = (const float*)d_in[2];
  const float* Wk    = (const float*)d_in[3];
  const float* bk    = (const float*)d_in[4];
  const float* Wv    = (const float*)d_in[5];
  const float* bv    = (const float*)d_in[6];
  const float* Wo    = (const float*)d_in[7];
  const float* bo    = (const float*)d_in[8];
  const float* gamma = (const float*)d_in[9];
  const float* beta  = (const float*)d_in[10];
  const float* Wg    = (const float*)d_in[11];
  const float* We    = (const float*)d_in[12];
  const float* be    = (const float*)d_in[13];
  float* out = (float*)d_out;
  char* ws = (char*)d_ws;

  // ---- layout, peak exactly 40,239,104 B (== proven peak) ----
  // [0, 393216):          gate | idx | cnt | best
  // phase 1 (slab loop, serial qkv->attn):
  //   [393216, 19267584):   Wq/Wk/Wv split planes (9 x 2 MB)
  //   [19267584, 29753344): k slab (2560 rows x 4 KB)
  //   [29753344, 40239104): v slab
  //   q slabs live in d_out rows (attn overwrites them in-place with o)
  // phase 2 (wo..moe):
  //   [393216, 33947648):  t (8192 x 4 KB) over dead planes/slabs
  //     h16 = first 2 KB of each t row; we16 = second 2 KB
  //   [33947648, 40239104): Wo split planes (prepped after slab loop)
  const size_t GATE_OFF = 0;
  const size_t IDX_OFF  = 32768;
  const size_t CNT_OFF  = IDX_OFF + (size_t)8 * NTOK * 4;   // 294912
  const size_t BEST_OFF = CNT_OFF + 256;                    // 295168
  const size_t WQKV_OFF = 393216;
  const size_t K_OFF    = WQKV_OFF + (size_t)9 * 1048576 * 2;  // 19267584
  const size_t V_OFF    = K_OFF + (size_t)SLAB * KD * 4;       // 29753344
  const size_t T_OFF    = 393216;
  const size_t WOP_OFF  = T_OFF + (size_t)NTOK * KD * 4;       // 33947648

  float* gate = (float*)(ws + GATE_OFF);
  int*   idx  = (int*)(ws + IDX_OFF);
  int*   cnt  = (int*)(ws + CNT_OFF);
  int*   best = (int*)(ws + BEST_OFF);
  u16*   wqkv = (u16*)(ws + WQKV_OFF);
  float* kbuf = (float*)(ws + K_OFF);
  float* vbuf = (float*)(ws + V_OFF);
  float* t    = (float*)(ws + T_OFF);
  u16*   t16  = (u16*)(ws + T_OFF);
  u16*   wop  = (u16*)(ws + WOP_OFF);

  prep_w<<<dim3(16, 16, 3), 256, 0, stream>>>(Wq, Wk, Wv, Wo, wqkv, wop, 0);

  // slabs: 2560, 2560, 2560, 512
  for (int tok0 = 0; tok0 < NTOK; tok0 += SLAB) {
    const int len = (NTOK - tok0 < SLAB) ? (NTOK - tok0) : SLAB;
    qkv_gemm<<<dim3(len / 128, 8, 3), 256, 0, stream>>>(
        x, wqkv, bq, bk, bv, out + (size_t)tok0 * KD, kbuf, vbuf, tok0);
    attn_fp32<<<dim3(len / 64 * 16), 256, 0, stream>>>(
        out + (size_t)tok0 * KD, kbuf, vbuf);
  }

  prep_w<<<dim3(16, 16, 1), 256, 0, stream>>>(Wq, Wk, Wv, Wo, wqkv, wop, 3);
  wo_gemm<<<dim3(NTOK / 128, 8), 256, 0, stream>>>(out, wop, bo, x, t);
  ln_gate<<<dim3(NTOK), 256, 0, stream>>>(t, gamma, beta, Wg, gate, best, t16);
  prep_we<<<dim3(16, 16, 8), 256, 0, stream>>>(We, t16);
  bucket_sort<<<dim3(1), 256, 0, stream>>>(best, idx, cnt);
  // grid 1280 = 20 m x 8 y x 8 e via XCD-stable bijection (decode in-kernel)
  moe_gemm<<<dim3(1280), 256, 0, stream>>>(t16, be, gate, idx, cnt, out);
}